// Round 1
// baseline (5555.205 us; speedup 1.0000x reference)
//
#include <hip/hip_runtime.h>
#include <hip/hip_bf16.h>
#include <math.h>

#define BB 2
#define SS 4096
#define DDIM 2560
#define MMEM 128
#define NH 8
#define HDIM 320
#define SEG 1024
#define NSEG 4

typedef unsigned short u16;
typedef __attribute__((ext_vector_type(8))) short short8;
typedef __attribute__((ext_vector_type(4))) float f32x4;
typedef __attribute__((ext_vector_type(4))) int int4v;

__device__ __forceinline__ u16 f2b(float x) {
  __hip_bfloat16 h = __float2bfloat16(x);
  return *reinterpret_cast<u16*>(&h);
}

// ---------------- generic batched MFMA GEMM: C = alpha * A @ Bt^T (+bias) ----------------
// A: (Mr x K) bf16, row stride lda. Bt: (N x K) bf16 (i.e. B transposed), row stride ldb.
// z = z2*Z1 + z1 batching with independent strides for each operand.
#define GF_F32   1
#define GF_BF16  2
#define GF_TRANS 4
#define GF_BIAS  8

__global__ __launch_bounds__(256) void gemm_bt(
    const u16* __restrict__ A, const u16* __restrict__ Bt,
    float* __restrict__ Cf, u16* __restrict__ Cb,
    const float* __restrict__ bias,
    int Mr, int N, int K,
    long lda, long ldb, long ldcf, long ldcb,
    long sA1, long sA2, long sB1, long sB2,
    long sCf1, long sCf2, long sCb1, long sCb2,
    int Z1, float alpha, int flags)
{
  __shared__ __align__(16) u16 As[128][40];
  __shared__ __align__(16) u16 Bs[128][40];

  int z = blockIdx.z;
  int z1 = z % Z1, z2 = z / Z1;
  const u16* Az = A + (long)z1 * sA1 + (long)z2 * sA2;
  const u16* Bz = Bt + (long)z1 * sB1 + (long)z2 * sB2;

  int tM = blockIdx.x * 128;
  int tN = blockIdx.y * 128;

  int t = threadIdx.x;
  int lane = t & 63;
  int w = t >> 6;
  int wm = w & 1, wn = w >> 1;

  f32x4 acc[4][4];
#pragma unroll
  for (int i = 0; i < 4; i++)
#pragma unroll
    for (int j = 0; j < 4; j++) acc[i][j] = (f32x4){0.f, 0.f, 0.f, 0.f};

  int arow = lane & 15;
  int kq = (lane >> 4) << 3;

  for (int k0 = 0; k0 < K; k0 += 32) {
    __syncthreads();
#pragma unroll
    for (int ph = 0; ph < 2; ph++) {
      int c = t + ph * 256;
      int r = c >> 2;
      int kc = (c & 3) << 3;
      int4v va = {0, 0, 0, 0};
      int gr = tM + r;
      if (gr < Mr) va = *(const int4v*)(Az + (long)gr * lda + (k0 + kc));
      *(int4v*)(&As[r][kc]) = va;
      int4v vb = {0, 0, 0, 0};
      int gn = tN + r;
      if (gn < N) vb = *(const int4v*)(Bz + (long)gn * ldb + (k0 + kc));
      *(int4v*)(&Bs[r][kc]) = vb;
    }
    __syncthreads();

    short8 af[4], bfr[4];
#pragma unroll
    for (int i = 0; i < 4; i++)
      af[i] = *(const short8*)(&As[wm * 64 + i * 16 + arow][kq]);
#pragma unroll
    for (int j = 0; j < 4; j++)
      bfr[j] = *(const short8*)(&Bs[wn * 64 + j * 16 + arow][kq]);
#pragma unroll
    for (int i = 0; i < 4; i++)
#pragma unroll
      for (int j = 0; j < 4; j++)
        acc[i][j] = __builtin_amdgcn_mfma_f32_16x16x32_bf16(af[i], bfr[j], acc[i][j], 0, 0, 0);
  }

  long cfo = (long)z1 * sCf1 + (long)z2 * sCf2;
  long cbo = (long)z1 * sCb1 + (long)z2 * sCb2;
#pragma unroll
  for (int i = 0; i < 4; i++) {
#pragma unroll
    for (int j = 0; j < 4; j++) {
      int col = tN + wn * 64 + j * 16 + (lane & 15);
      int rb = tM + wm * 64 + i * 16 + ((lane >> 4) << 2);
      if (col < N) {
        float bv = (flags & GF_BIAS) ? bias[col] : 0.f;
#pragma unroll
        for (int r = 0; r < 4; r++) {
          int row = rb + r;
          if (row < Mr) {
            float x = acc[i][j][r] * alpha + bv;
            if (flags & GF_F32)  Cf[cfo + (long)row * ldcf + col] = x;
            if (flags & GF_BF16) Cb[cbo + (long)row * ldcb + col] = f2b(x);
            if (flags & GF_TRANS) Cb[cbo + (long)col * ldcb + row] = f2b(x);
          }
        }
      }
    }
  }
}

// ---------------- helpers ----------------
__global__ void conv_bf16(const float* __restrict__ X, u16* __restrict__ Y, long n4) {
  long i = (long)blockIdx.x * 256 + threadIdx.x;
  if (i < n4) {
    float4 v = ((const float4*)X)[i];
    ushort4 o;
    o.x = f2b(v.x); o.y = f2b(v.y); o.z = f2b(v.z); o.w = f2b(v.w);
    ((ushort4*)Y)[i] = o;
  }
}

// W (K x N) fp32 -> Wt (N x K) bf16
__global__ __launch_bounds__(256) void transpose_conv(const float* __restrict__ W, u16* __restrict__ Wt, int K, int N) {
  __shared__ float tile[32][33];
  int nb = blockIdx.x * 32;
  int kb = blockIdx.y * 32;
  int tx = threadIdx.x & 31, ty = threadIdx.x >> 5;
  for (int r = ty; r < 32; r += 8) {
    int k = kb + r, n = nb + tx;
    tile[r][tx] = (k < K && n < N) ? W[(long)k * N + n] : 0.f;
  }
  __syncthreads();
  for (int r = ty; r < 32; r += 8) {
    int n = nb + r, k = kb + tx;
    if (n < N && k < K) Wt[(long)n * K + k] = f2b(tile[tx][r]);
  }
}

__global__ void init_mem(const float* __restrict__ im, float* __restrict__ mf, u16* __restrict__ mb,
                         long perB, long total) {
  long i = (long)blockIdx.x * 256 + threadIdx.x;
  if (i < total) { float v = im[i % perB]; mf[i] = v; mb[i] = f2b(v); }
}

__global__ __launch_bounds__(256) void softmax_rows(const float* __restrict__ S, u16* __restrict__ P, int len) {
  __shared__ float e[1024];
  __shared__ float red[4];
  long row = blockIdx.x;
  const float* x = S + row * (long)len;
  u16* pp = P + row * (long)len;
  int t = threadIdx.x;
  float mx = -3.4e38f;
  for (int i = t; i < len; i += 256) mx = fmaxf(mx, x[i]);
  for (int o = 32; o; o >>= 1) mx = fmaxf(mx, __shfl_xor(mx, o));
  if ((t & 63) == 0) red[t >> 6] = mx;
  __syncthreads();
  mx = fmaxf(fmaxf(red[0], red[1]), fmaxf(red[2], red[3]));
  __syncthreads();
  float sum = 0.f;
  for (int i = t; i < len; i += 256) { float v = __expf(x[i] - mx); e[i] = v; sum += v; }
  for (int o = 32; o; o >>= 1) sum += __shfl_xor(sum, o);
  if ((t & 63) == 0) red[t >> 6] = sum;
  __syncthreads();
  sum = red[0] + red[1] + red[2] + red[3];
  float inv = 1.f / sum;
  for (int i = t; i < len; i += 256) pp[i] = f2b(e[i] * inv);
}

// h = seg + sigmoid(gpre) * o ; write fp32 to out (segment slot) and bf16 copy
__global__ void h_kernel(const float* __restrict__ hs, const float* __restrict__ gpre,
                         const float* __restrict__ o, float* __restrict__ out,
                         u16* __restrict__ hb, long segoff) {
  long idx = (long)blockIdx.x * 256 + threadIdx.x;
  const long per = (long)SEG * DDIM;
  long b = idx / per, r = idx - b * per;
  long io = b * (long)SS * DDIM + segoff + r;
  float g = 1.f / (1.f + __expf(-gpre[idx]));
  float h = hs[io] + g * o[idx];
  out[io] = h;
  hb[idx] = f2b(h);
}

__global__ void concat_mem(const u16* __restrict__ a, const u16* __restrict__ b, u16* __restrict__ c) {
  long idx = (long)blockIdx.x * 256 + threadIdx.x;
  long row = idx / (2 * DDIM);
  long col = idx - row * (2 * DDIM);
  c[idx] = (col < DDIM) ? a[row * DDIM + col] : b[row * DDIM + col - DDIM];
}

__global__ void update_mem(const float* __restrict__ gp, const float* __restrict__ nm,
                           float* __restrict__ mf, u16* __restrict__ mb) {
  long idx = (long)blockIdx.x * 256 + threadIdx.x;
  float g = 1.f / (1.f + __expf(-gp[idx]));
  float v = g * nm[idx] + (1.f - g) * mf[idx];
  mf[idx] = v;
  mb[idx] = f2b(v);
}

// ---------------- host ----------------
static inline void launch_gemm(hipStream_t st,
    const void* A, const void* Bt, void* Cf, void* Cb, const void* bias,
    int Mr, int N, int K,
    long lda, long ldb, long ldcf, long ldcb,
    long sA1, long sA2, long sB1, long sB2,
    long sCf1, long sCf2, long sCb1, long sCb2,
    int Z1, int Z2, float alpha, int flags)
{
  dim3 grid((Mr + 127) / 128, (N + 127) / 128, Z1 * Z2);
  gemm_bt<<<grid, dim3(256), 0, st>>>(
      (const u16*)A, (const u16*)Bt, (float*)Cf, (u16*)Cb, (const float*)bias,
      Mr, N, K, lda, ldb, ldcf, ldcb, sA1, sA2, sB1, sB2, sCf1, sCf2, sCb1, sCb2,
      Z1, alpha, flags);
}

extern "C" void kernel_launch(void* const* d_in, const int* in_sizes, int n_in,
                              void* d_out, int out_size, void* d_ws, size_t ws_size,
                              hipStream_t stream) {
  const float* hs   = (const float*)d_in[0];
  const float* imem = (const float*)d_in[1];
  const float* wq_r = (const float*)d_in[2];
  const float* wk_r = (const float*)d_in[3];
  const float* wv_r = (const float*)d_in[4];
  const float* wo_r = (const float*)d_in[5];
  const float* wg_r = (const float*)d_in[6];
  const float* bg_r = (const float*)d_in[7];
  const float* wqin = (const float*)d_in[8];
  const float* wq_w = (const float*)d_in[9];
  const float* wk_w = (const float*)d_in[10];
  const float* wv_w = (const float*)d_in[11];
  const float* wo_w = (const float*)d_in[12];
  const float* wg_w = (const float*)d_in[13];
  const float* bg_w = (const float*)d_in[14];
  float* out = (float*)d_out;

  const long D = DDIM, M = MMEM, S = SS, B = BB, H = NH, HD = HDIM, L = SEG;
  const float iscale = 1.f / sqrtf((float)HDIM);

  char* p = (char*)d_ws;
  auto alc = [&](size_t bytes) -> void* {
    void* r = (void*)p; p += (bytes + 255) & ~(size_t)255; return r;
  };

  u16* hs_b  = (u16*)alc(B * S * D * 2);
  u16* wqrT  = (u16*)alc(D * D * 2);
  u16* wkrT  = (u16*)alc(D * D * 2);
  u16* wvrT  = (u16*)alc(D * D * 2);
  u16* worT  = (u16*)alc(D * D * 2);
  u16* wgrT  = (u16*)alc(D * D * 2);
  u16* wkwT  = (u16*)alc(D * D * 2);
  u16* wvwT  = (u16*)alc(D * D * 2);
  u16* wowT  = (u16*)alc(D * D * 2);
  u16* wqwT  = (u16*)alc(D * D * 2);
  u16* wgwT  = (u16*)alc(2 * D * D * 2);
  u16* wq_b  = (u16*)alc(M * D * 2);
  u16* q_w   = (u16*)alc(M * D * 2);
  float* mem_f = (float*)alc(B * M * D * 4);
  u16*   mem_b = (u16*)alc(B * M * D * 2);
  float* nm_f  = (float*)alc(B * M * D * 4);
  u16*   nm_b  = (u16*)alc(B * M * D * 2);
  u16* q_r   = (u16*)alc(B * L * D * 2);
  u16* k_r   = (u16*)alc(B * M * D * 2);
  u16* v_rT  = (u16*)alc(D * B * M * 2);
  float* sc_r = (float*)alc(B * H * L * M * 4);
  u16*   pr_r = (u16*)alc(B * H * L * M * 2);
  u16* ctx   = (u16*)alc(B * L * D * 2);
  float* gpre = (float*)alc(B * L * D * 4);
  float* obuf = (float*)alc(B * L * D * 4);
  u16* h_b   = (u16*)alc(B * L * D * 2);
  u16* k_w   = (u16*)alc(B * L * D * 2);
  u16* v_wT  = (u16*)alc(D * B * L * 2);
  float* sc_w = (float*)alc(B * H * M * L * 4);
  u16*   pr_w = (u16*)alc(B * H * M * L * 2);
  u16* att_w = (u16*)alc(B * M * D * 2);
  u16* cat   = (u16*)alc(B * M * 2 * D * 2);
  float* gpre_w = (float*)alc(B * M * D * 4);

  // ---- one-time preprocessing ----
  conv_bf16<<<(unsigned)((B * S * D / 4 + 255) / 256), 256, 0, stream>>>(hs, hs_b, B * S * D / 4);
  dim3 tg(D / 32, D / 32);
  transpose_conv<<<tg, 256, 0, stream>>>(wq_r, wqrT, (int)D, (int)D);
  transpose_conv<<<tg, 256, 0, stream>>>(wk_r, wkrT, (int)D, (int)D);
  transpose_conv<<<tg, 256, 0, stream>>>(wv_r, wvrT, (int)D, (int)D);
  transpose_conv<<<tg, 256, 0, stream>>>(wo_r, worT, (int)D, (int)D);
  transpose_conv<<<tg, 256, 0, stream>>>(wg_r, wgrT, (int)D, (int)D);
  transpose_conv<<<tg, 256, 0, stream>>>(wk_w, wkwT, (int)D, (int)D);
  transpose_conv<<<tg, 256, 0, stream>>>(wv_w, wvwT, (int)D, (int)D);
  transpose_conv<<<tg, 256, 0, stream>>>(wo_w, wowT, (int)D, (int)D);
  transpose_conv<<<tg, 256, 0, stream>>>(wq_w, wqwT, (int)D, (int)D);
  transpose_conv<<<dim3(D / 32, 2 * D / 32), 256, 0, stream>>>(wg_w, wgwT, (int)(2 * D), (int)D);
  conv_bf16<<<(unsigned)((M * D / 4 + 255) / 256), 256, 0, stream>>>(wqin, wq_b, M * D / 4);
  init_mem<<<(unsigned)((B * M * D + 255) / 256), 256, 0, stream>>>(imem, mem_f, mem_b, M * D, B * M * D);

  // q_w = write_queries @ wq_w  (batch/segment invariant)
  launch_gemm(stream, wq_b, wqwT, nullptr, q_w, nullptr,
              (int)M, (int)D, (int)D, D, D, 0, D,
              0, 0, 0, 0, 0, 0, 0, 0, 1, 1, 1.f, GF_BF16);

  for (int i = 0; i < NSEG; i++) {
    long so = (long)i * L * D;  // element offset of segment within one batch of hs

    // q_r = seg @ wq_r  -> (B, L, D) bf16
    launch_gemm(stream, hs_b + so, wqrT, nullptr, q_r, nullptr,
                (int)L, (int)D, (int)D, D, D, 0, D,
                0, S * D, 0, 0, 0, 0, 0, L * D, 1, (int)B, 1.f, GF_BF16);
    // k_r = mem @ wk_r  -> (B*M, D) bf16
    launch_gemm(stream, mem_b, wkrT, nullptr, k_r, nullptr,
                (int)(B * M), (int)D, (int)D, D, D, 0, D,
                0, 0, 0, 0, 0, 0, 0, 0, 1, 1, 1.f, GF_BF16);
    // v_rT = (mem @ wv_r)^T -> (D, B*M) bf16
    launch_gemm(stream, mem_b, wvrT, nullptr, v_rT, nullptr,
                (int)(B * M), (int)D, (int)D, D, D, 0, B * M,
                0, 0, 0, 0, 0, 0, 0, 0, 1, 1, 1.f, GF_TRANS);
    // scores_r = q_r . k_r^T / sqrt(hd) -> (B,H,L,M) fp32
    launch_gemm(stream, q_r, k_r, sc_r, nullptr, nullptr,
                (int)L, (int)M, (int)HD, D, D, M, 0,
                HD, L * D, HD, M * D, L * M, H * L * M, 0, 0,
                (int)H, (int)B, iscale, GF_F32);
    softmax_rows<<<(unsigned)(B * H * L), 256, 0, stream>>>(sc_r, pr_r, (int)M);
    // ctx = probs @ v -> (B,L,D) bf16
    launch_gemm(stream, pr_r, v_rT, nullptr, ctx, nullptr,
                (int)L, (int)HD, (int)M, M, B * M, 0, D,
                L * M, H * L * M, HD * B * M, M, 0, 0, HD, L * D,
                (int)H, (int)B, 1.f, GF_BF16);
    // gpre = seg @ wg_r + bg_r -> fp32
    launch_gemm(stream, hs_b + so, wgrT, gpre, nullptr, bg_r,
                (int)L, (int)D, (int)D, D, D, D, 0,
                0, S * D, 0, 0, 0, L * D, 0, 0, 1, (int)B, 1.f, GF_F32 | GF_BIAS);
    // obuf = ctx @ wo_r -> fp32
    launch_gemm(stream, ctx, worT, obuf, nullptr, nullptr,
                (int)L, (int)D, (int)D, D, D, D, 0,
                0, L * D, 0, 0, 0, L * D, 0, 0, 1, (int)B, 1.f, GF_F32);
    // h = seg + sigmoid(gpre)*obuf  -> d_out + bf16 copy
    h_kernel<<<(unsigned)(B * L * D / 256), 256, 0, stream>>>(hs, gpre, obuf, out, h_b, so);

    // k_w = h @ wk_w -> (B*L, D) bf16
    launch_gemm(stream, h_b, wkwT, nullptr, k_w, nullptr,
                (int)(B * L), (int)D, (int)D, D, D, 0, D,
                0, 0, 0, 0, 0, 0, 0, 0, 1, 1, 1.f, GF_BF16);
    // v_wT = (h @ wv_w)^T -> (D, B*L) bf16
    launch_gemm(stream, h_b, wvwT, nullptr, v_wT, nullptr,
                (int)(B * L), (int)D, (int)D, D, D, 0, B * L,
                0, 0, 0, 0, 0, 0, 0, 0, 1, 1, 1.f, GF_TRANS);
    // scores_w = q_w . k_w^T / sqrt(hd) -> (B,H,M,L) fp32
    launch_gemm(stream, q_w, k_w, sc_w, nullptr, nullptr,
                (int)M, (int)L, (int)HD, D, D, L, 0,
                HD, 0, HD, L * D, M * L, H * M * L, 0, 0,
                (int)H, (int)B, iscale, GF_F32);
    softmax_rows<<<(unsigned)(B * H * M), 256, 0, stream>>>(sc_w, pr_w, (int)L);
    // att_w = probs_w @ v_w -> (B,M,D) bf16
    launch_gemm(stream, pr_w, v_wT, nullptr, att_w, nullptr,
                (int)M, (int)HD, (int)L, L, B * L, 0, D,
                M * L, H * M * L, HD * B * L, L, 0, 0, HD, M * D,
                (int)H, (int)B, 1.f, GF_BF16);
    // new_mem = att_w @ wo_w -> fp32 + bf16 (seg 0 writes memory directly)
    float* nmf = (i == 0) ? mem_f : nm_f;
    u16*   nmb = (i == 0) ? mem_b : nm_b;
    launch_gemm(stream, att_w, wowT, nmf, nmb, nullptr,
                (int)(B * M), (int)D, (int)D, D, D, D, D,
                0, 0, 0, 0, 0, 0, 0, 0, 1, 1, 1.f, GF_F32 | GF_BF16);
    if (i > 0) {
      concat_mem<<<(unsigned)(B * M * 2 * D / 256), 256, 0, stream>>>(mem_b, nm_b, cat);
      launch_gemm(stream, cat, wgwT, gpre_w, nullptr, bg_w,
                  (int)(B * M), (int)D, (int)(2 * D), 2 * D, 2 * D, D, 0,
                  0, 0, 0, 0, 0, 0, 0, 0, 1, 1, 1.f, GF_F32 | GF_BIAS);
      update_mem<<<(unsigned)(B * M * D / 256), 256, 0, stream>>>(gpre_w, nm_f, mem_f, mem_b);
    }
  }
}

// Round 2
// 3208.527 us; speedup vs baseline: 1.7314x; 1.7314x over previous
//
#include <hip/hip_runtime.h>
#include <hip/hip_bf16.h>
#include <math.h>

#define BB 2
#define SS 4096
#define DDIM 2560
#define MMEM 128
#define NH 8
#define HDIM 320
#define SEG 1024
#define NSEG 4

typedef unsigned short u16;
typedef __attribute__((ext_vector_type(8))) short short8;
typedef __attribute__((ext_vector_type(4))) float f32x4;

__device__ __forceinline__ u16 f2b(float x) {
  __hip_bfloat16 h = __float2bfloat16(x);
  return *reinterpret_cast<u16*>(&h);
}

__device__ __forceinline__ void gll16(const u16* g, u16* l) {
  __builtin_amdgcn_global_load_lds(
      (__attribute__((address_space(1))) void*)g,
      (__attribute__((address_space(3))) void*)l, 16, 0, 0);
}

// Per-region output descriptor. Any non-null pointer gets written.
// f/b share geometry (ld, s1, s2); bt is bf16 transposed (ldt, s1, s2).
struct OutDesc {
  float* f; u16* b; u16* bt; const float* bias;
  long ld; long ldt; long s1; long s2;
};

// C = alpha * A @ Bt^T. A: (Mr x K) bf16 (Mr multiple of 128). Bt: (N x K) bf16.
// Region 0 covers cols [0,Nsplit), region 1 covers [Nsplit,N).
__global__ __launch_bounds__(256) void gemm_bt(
    const u16* __restrict__ A, const u16* __restrict__ Bt,
    OutDesc o0, OutDesc o1, int Nsplit,
    int N, int K, long lda, long ldb,
    long sA1, long sA2, long sB1, long sB2,
    int Z1, float alpha)
{
  __shared__ __align__(16) u16 sm[8192];   // As[128][32] + Bs[128][32], unpadded
  u16* As = sm;
  u16* Bs = sm + 4096;

  int z = blockIdx.z;
  int z1 = z % Z1, z2 = z / Z1;
  const u16* Az = A + (long)z1 * sA1 + (long)z2 * sA2 + (long)blockIdx.x * 128 * lda;
  const u16* Bz = Bt + (long)z1 * sB1 + (long)z2 * sB2;

  int tN = blockIdx.y * 128;
  int t = threadIdx.x;
  int lane = t & 63, w = t >> 6;
  int wm = w & 1, wn = w >> 1;

  // ---- staging addresses (global_load_lds, 16B per lane) ----
  int rr = t >> 2;               // 0..63
  int c8 = (t & 3) << 3;         // 0,8,16,24
  int n0 = tN + rr;      if (n0 > N - 1) n0 = N - 1;   // clamp edge N tiles
  int n1 = tN + 64 + rr; if (n1 > N - 1) n1 = N - 1;
  const u16* ga0 = Az + (long)rr * lda + c8;
  const u16* ga1 = Az + (long)(rr + 64) * lda + c8;
  const u16* gb0 = Bz + (long)n0 * ldb + c8;
  const u16* gb1 = Bz + (long)n1 * ldb + c8;
  u16* lA0 = As + t * 8;         // lds dest = wave base + lane*16B (contiguous)
  u16* lA1 = As + 2048 + t * 8;
  u16* lB0 = Bs + t * 8;
  u16* lB1 = Bs + 2048 + t * 8;

  f32x4 acc[4][4];
#pragma unroll
  for (int i = 0; i < 4; i++)
#pragma unroll
    for (int j = 0; j < 4; j++) acc[i][j] = (f32x4){0.f, 0.f, 0.f, 0.f};

  int arow = lane & 15;
  int kq = (lane >> 4) << 3;

  for (int k0 = 0; k0 < K; k0 += 32) {
    gll16(ga0, lA0); gll16(ga1, lA1);
    gll16(gb0, lB0); gll16(gb1, lB1);
    ga0 += 32; ga1 += 32; gb0 += 32; gb1 += 32;
    __syncthreads();   // drains vmcnt, publishes LDS

    short8 af[4], bfr[4];
#pragma unroll
    for (int i = 0; i < 4; i++)
      af[i] = *(const short8*)(As + (wm * 64 + i * 16 + arow) * 32 + kq);
#pragma unroll
    for (int j = 0; j < 4; j++)
      bfr[j] = *(const short8*)(Bs + (wn * 64 + j * 16 + arow) * 32 + kq);
#pragma unroll
    for (int i = 0; i < 4; i++)
#pragma unroll
      for (int j = 0; j < 4; j++)
        acc[i][j] = __builtin_amdgcn_mfma_f32_16x16x32_bf16(af[i], bfr[j], acc[i][j], 0, 0, 0);
    __syncthreads();   // all waves done reading before next overwrite
  }

  // ---- epilogue ----
  int rowb = blockIdx.x * 128 + wm * 64 + ((lane >> 4) << 2);
#pragma unroll
  for (int i = 0; i < 4; i++) {
    int row = rowb + i * 16;
#pragma unroll
    for (int j = 0; j < 4; j++) {
      int cl = tN + wn * 64 + j * 16 + arow;
      if (cl >= N) continue;
      const OutDesc& d = (cl < Nsplit) ? o0 : o1;
      int c = (cl < Nsplit) ? cl : cl - Nsplit;
      long co = (long)z1 * d.s1 + (long)z2 * d.s2;
      float bv = d.bias ? d.bias[c] : 0.f;
      float x0 = acc[i][j][0] * alpha + bv;
      float x1 = acc[i][j][1] * alpha + bv;
      float x2 = acc[i][j][2] * alpha + bv;
      float x3 = acc[i][j][3] * alpha + bv;
      if (d.f) {
        d.f[co + (long)(row + 0) * d.ld + c] = x0;
        d.f[co + (long)(row + 1) * d.ld + c] = x1;
        d.f[co + (long)(row + 2) * d.ld + c] = x2;
        d.f[co + (long)(row + 3) * d.ld + c] = x3;
      }
      if (d.b) {
        d.b[co + (long)(row + 0) * d.ld + c] = f2b(x0);
        d.b[co + (long)(row + 1) * d.ld + c] = f2b(x1);
        d.b[co + (long)(row + 2) * d.ld + c] = f2b(x2);
        d.b[co + (long)(row + 3) * d.ld + c] = f2b(x3);
      }
      if (d.bt) {
        ushort4 v;
        v.x = f2b(x0); v.y = f2b(x1); v.z = f2b(x2); v.w = f2b(x3);
        *(ushort4*)(d.bt + co + (long)c * d.ldt + row) = v;
      }
    }
  }
}

// ---------------- helpers ----------------
__global__ void conv_bf16(const float* __restrict__ X, u16* __restrict__ Y, long n4) {
  long i = (long)blockIdx.x * 256 + threadIdx.x;
  if (i < n4) {
    float4 v = ((const float4*)X)[i];
    ushort4 o;
    o.x = f2b(v.x); o.y = f2b(v.y); o.z = f2b(v.z); o.w = f2b(v.w);
    ((ushort4*)Y)[i] = o;
  }
}

// W (K x N) fp32 -> Wt (N x K) bf16
__global__ __launch_bounds__(256) void transpose_conv(const float* __restrict__ W, u16* __restrict__ Wt, int K, int N) {
  __shared__ float tile[32][33];
  int nb = blockIdx.x * 32;
  int kb = blockIdx.y * 32;
  int tx = threadIdx.x & 31, ty = threadIdx.x >> 5;
  for (int r = ty; r < 32; r += 8) {
    int k = kb + r, n = nb + tx;
    tile[r][tx] = (k < K && n < N) ? W[(long)k * N + n] : 0.f;
  }
  __syncthreads();
  for (int r = ty; r < 32; r += 8) {
    int n = nb + r, k = kb + tx;
    if (n < N && k < K) Wt[(long)n * K + k] = f2b(tile[tx][r]);
  }
}

__global__ void init_mem(const float* __restrict__ im, float* __restrict__ mf, u16* __restrict__ mb,
                         long perB, long total) {
  long i = (long)blockIdx.x * 256 + threadIdx.x;
  if (i < total) { float v = im[i % perB]; mf[i] = v; mb[i] = f2b(v); }
}

__global__ __launch_bounds__(256) void softmax_rows(const float* __restrict__ S, u16* __restrict__ P, int len) {
  __shared__ float e[1024];
  __shared__ float red[4];
  long row = blockIdx.x;
  const float* x = S + row * (long)len;
  u16* pp = P + row * (long)len;
  int t = threadIdx.x;
  float mx = -3.4e38f;
  for (int i = t; i < len; i += 256) mx = fmaxf(mx, x[i]);
  for (int o = 32; o; o >>= 1) mx = fmaxf(mx, __shfl_xor(mx, o));
  if ((t & 63) == 0) red[t >> 6] = mx;
  __syncthreads();
  mx = fmaxf(fmaxf(red[0], red[1]), fmaxf(red[2], red[3]));
  __syncthreads();
  float sum = 0.f;
  for (int i = t; i < len; i += 256) { float v = __expf(x[i] - mx); e[i] = v; sum += v; }
  for (int o = 32; o; o >>= 1) sum += __shfl_xor(sum, o);
  if ((t & 63) == 0) red[t >> 6] = sum;
  __syncthreads();
  sum = red[0] + red[1] + red[2] + red[3];
  float inv = 1.f / sum;
  for (int i = t; i < len; i += 256) pp[i] = f2b(e[i] * inv);
}

__global__ void h_kernel(const float* __restrict__ hs, const float* __restrict__ gpre,
                         const float* __restrict__ o, float* __restrict__ out,
                         u16* __restrict__ hb, long segoff) {
  long idx = (long)blockIdx.x * 256 + threadIdx.x;
  const long per = (long)SEG * DDIM;
  long b = idx / per, r = idx - b * per;
  long io = b * (long)SS * DDIM + segoff + r;
  float g = 1.f / (1.f + __expf(-gpre[idx]));
  float h = hs[io] + g * o[idx];
  out[io] = h;
  hb[idx] = f2b(h);
}

__global__ void concat_mem(const u16* __restrict__ a, const u16* __restrict__ b, u16* __restrict__ c) {
  long idx = (long)blockIdx.x * 256 + threadIdx.x;
  long row = idx / (2 * DDIM);
  long col = idx - row * (2 * DDIM);
  c[idx] = (col < DDIM) ? a[row * DDIM + col] : b[row * DDIM + col - DDIM];
}

__global__ void update_mem(const float* __restrict__ gp, const float* __restrict__ nm,
                           float* __restrict__ mf, u16* __restrict__ mb) {
  long idx = (long)blockIdx.x * 256 + threadIdx.x;
  float g = 1.f / (1.f + __expf(-gp[idx]));
  float v = g * nm[idx] + (1.f - g) * mf[idx];
  mf[idx] = v;
  mb[idx] = f2b(v);
}

// ---------------- host ----------------
static inline OutDesc OD0() {
  OutDesc d; d.f = nullptr; d.b = nullptr; d.bt = nullptr; d.bias = nullptr;
  d.ld = 0; d.ldt = 0; d.s1 = 0; d.s2 = 0; return d;
}

static inline void launch_gemm(hipStream_t st, const void* A, const void* Bt,
    OutDesc o0, OutDesc o1, int Nsplit, int Mr, int N, int K,
    long lda, long ldb, long sA1, long sA2, long sB1, long sB2,
    int Z1, int Z2, float alpha)
{
  dim3 grid(Mr / 128, (N + 127) / 128, Z1 * Z2);
  gemm_bt<<<grid, dim3(256), 0, st>>>((const u16*)A, (const u16*)Bt, o0, o1,
      Nsplit, N, K, lda, ldb, sA1, sA2, sB1, sB2, Z1, alpha);
}

extern "C" void kernel_launch(void* const* d_in, const int* in_sizes, int n_in,
                              void* d_out, int out_size, void* d_ws, size_t ws_size,
                              hipStream_t stream) {
  const float* hs   = (const float*)d_in[0];
  const float* imem = (const float*)d_in[1];
  const float* wq_r = (const float*)d_in[2];
  const float* wk_r = (const float*)d_in[3];
  const float* wv_r = (const float*)d_in[4];
  const float* wo_r = (const float*)d_in[5];
  const float* wg_r = (const float*)d_in[6];
  const float* bg_r = (const float*)d_in[7];
  const float* wqin = (const float*)d_in[8];
  const float* wq_w = (const float*)d_in[9];
  const float* wk_w = (const float*)d_in[10];
  const float* wv_w = (const float*)d_in[11];
  const float* wo_w = (const float*)d_in[12];
  const float* wg_w = (const float*)d_in[13];
  const float* bg_w = (const float*)d_in[14];
  float* out = (float*)d_out;

  const long D = DDIM, M = MMEM, S = SS, B = BB, H = NH, HD = HDIM, L = SEG;
  const float iscale = 1.f / sqrtf((float)HDIM);

  char* p = (char*)d_ws;
  auto alc = [&](size_t bytes) -> void* {
    void* r = (void*)p; p += (bytes + 255) & ~(size_t)255; return r;
  };

  u16* hs_b  = (u16*)alc(B * S * D * 2);
  u16* wqgT  = (u16*)alc(2 * D * D * 2);   // [wq_r^T ; wg_r^T]
  u16* wkvrT = (u16*)alc(2 * D * D * 2);   // [wk_r^T ; wv_r^T]
  u16* wkvwT = (u16*)alc(2 * D * D * 2);   // [wk_w^T ; wv_w^T]
  u16* worT  = (u16*)alc(D * D * 2);
  u16* wowT  = (u16*)alc(D * D * 2);
  u16* wqwT  = (u16*)alc(D * D * 2);
  u16* wgwT  = (u16*)alc(2 * D * D * 2);   // (D rows, 2D cols each row)
  u16* wq_b  = (u16*)alc(M * D * 2);
  u16* q_w   = (u16*)alc(M * D * 2);
  float* mem_f = (float*)alc(B * M * D * 4);
  u16*   mem_b = (u16*)alc(B * M * D * 2);
  float* nm_f  = (float*)alc(B * M * D * 4);
  u16*   nm_b  = (u16*)alc(B * M * D * 2);
  u16* q_r   = (u16*)alc(B * L * D * 2);
  u16* k_r   = (u16*)alc(B * M * D * 2);
  u16* v_rT  = (u16*)alc(D * B * M * 2);
  float* sc_r = (float*)alc(B * H * L * M * 4);
  u16*   pr_r = (u16*)alc(B * H * L * M * 2);
  u16* ctx   = (u16*)alc(B * L * D * 2);
  float* gpre = (float*)alc(B * L * D * 4);
  float* obuf = (float*)alc(B * L * D * 4);
  u16* h_b   = (u16*)alc(B * L * D * 2);
  u16* k_w   = (u16*)alc(B * L * D * 2);
  u16* v_wT  = (u16*)alc(D * B * L * 2);
  float* sc_w = (float*)alc(B * H * M * L * 4);
  u16*   pr_w = (u16*)alc(B * H * M * L * 2);
  u16* att_w = (u16*)alc(B * M * D * 2);
  u16* cat   = (u16*)alc(B * M * 2 * D * 2);
  float* gpre_w = (float*)alc(B * M * D * 4);

  // ---- one-time preprocessing ----
  conv_bf16<<<(unsigned)((B * S * D / 4 + 255) / 256), 256, 0, stream>>>(hs, hs_b, B * S * D / 4);
  dim3 tg(D / 32, D / 32);
  transpose_conv<<<tg, 256, 0, stream>>>(wq_r, wqgT,          (int)D, (int)D);
  transpose_conv<<<tg, 256, 0, stream>>>(wg_r, wqgT + D * D,  (int)D, (int)D);
  transpose_conv<<<tg, 256, 0, stream>>>(wk_r, wkvrT,         (int)D, (int)D);
  transpose_conv<<<tg, 256, 0, stream>>>(wv_r, wkvrT + D * D, (int)D, (int)D);
  transpose_conv<<<tg, 256, 0, stream>>>(wk_w, wkvwT,         (int)D, (int)D);
  transpose_conv<<<tg, 256, 0, stream>>>(wv_w, wkvwT + D * D, (int)D, (int)D);
  transpose_conv<<<tg, 256, 0, stream>>>(wo_r, worT, (int)D, (int)D);
  transpose_conv<<<tg, 256, 0, stream>>>(wo_w, wowT, (int)D, (int)D);
  transpose_conv<<<tg, 256, 0, stream>>>(wq_w, wqwT, (int)D, (int)D);
  transpose_conv<<<dim3(D / 32, 2 * D / 32), 256, 0, stream>>>(wg_w, wgwT, (int)(2 * D), (int)D);
  conv_bf16<<<(unsigned)((M * D / 4 + 255) / 256), 256, 0, stream>>>(wqin, wq_b, M * D / 4);
  init_mem<<<(unsigned)((B * M * D + 255) / 256), 256, 0, stream>>>(imem, mem_f, mem_b, M * D, B * M * D);

  // q_w = write_queries @ wq_w  (batch/segment invariant)
  {
    OutDesc o0 = OD0(); o0.b = q_w; o0.ld = D;
    launch_gemm(stream, wq_b, wqwT, o0, OD0(), (int)D, (int)M, (int)D, (int)D,
                D, D, 0, 0, 0, 0, 1, 1, 1.f);
  }

  for (int i = 0; i < NSEG; i++) {
    long so = (long)i * L * D;

    // [q_r | gpre] = seg @ [wq_r | wg_r]  (region0 bf16 q_r, region1 fp32+bias gpre)
    {
      OutDesc o0 = OD0(); o0.b = q_r;  o0.ld = D; o0.s2 = L * D;
      OutDesc o1 = OD0(); o1.f = gpre; o1.ld = D; o1.s2 = L * D; o1.bias = bg_r;
      launch_gemm(stream, hs_b + so, wqgT, o0, o1, (int)D, (int)L, (int)(2 * D), (int)D,
                  D, D, 0, S * D, 0, 0, 1, (int)B, 1.f);
    }
    // [k_r | v_rT] = mem @ [wk_r | wv_r]  (region1 transposed)
    {
      OutDesc o0 = OD0(); o0.b = k_r;  o0.ld = D;
      OutDesc o1 = OD0(); o1.bt = v_rT; o1.ldt = B * M;
      launch_gemm(stream, mem_b, wkvrT, o0, o1, (int)D, (int)(B * M), (int)(2 * D), (int)D,
                  D, D, 0, 0, 0, 0, 1, 1, 1.f);
    }
    // scores_r = q_r . k_r^T / sqrt(hd) -> (B,H,L,M) fp32
    {
      OutDesc o0 = OD0(); o0.f = sc_r; o0.ld = M; o0.s1 = L * M; o0.s2 = H * L * M;
      launch_gemm(stream, q_r, k_r, o0, OD0(), (int)M, (int)L, (int)M, (int)HD,
                  D, D, HD, L * D, HD, M * D, (int)H, (int)B, iscale);
    }
    softmax_rows<<<(unsigned)(B * H * L), 256, 0, stream>>>(sc_r, pr_r, (int)M);
    // ctx = probs @ v -> (B,L,D) bf16
    {
      OutDesc o0 = OD0(); o0.b = ctx; o0.ld = D; o0.s1 = HD; o0.s2 = L * D;
      launch_gemm(stream, pr_r, v_rT, o0, OD0(), (int)HD, (int)L, (int)HD, (int)M,
                  M, B * M, L * M, H * L * M, HD * B * M, M, (int)H, (int)B, 1.f);
    }
    // obuf = ctx @ wo_r -> fp32
    {
      OutDesc o0 = OD0(); o0.f = obuf; o0.ld = D; o0.s2 = L * D;
      launch_gemm(stream, ctx, worT, o0, OD0(), (int)D, (int)L, (int)D, (int)D,
                  D, D, 0, L * D, 0, 0, 1, (int)B, 1.f);
    }
    h_kernel<<<(unsigned)(B * L * D / 256), 256, 0, stream>>>(hs, gpre, obuf, out, h_b, so);

    // [k_w | v_wT] = h @ [wk_w | wv_w]
    {
      OutDesc o0 = OD0(); o0.b = k_w;  o0.ld = D;
      OutDesc o1 = OD0(); o1.bt = v_wT; o1.ldt = B * L;
      launch_gemm(stream, h_b, wkvwT, o0, o1, (int)D, (int)(B * L), (int)(2 * D), (int)D,
                  D, D, 0, 0, 0, 0, 1, 1, 1.f);
    }
    // scores_w = q_w . k_w^T / sqrt(hd) -> (B,H,M,L) fp32
    {
      OutDesc o0 = OD0(); o0.f = sc_w; o0.ld = L; o0.s1 = M * L; o0.s2 = H * M * L;
      launch_gemm(stream, q_w, k_w, o0, OD0(), (int)L, (int)M, (int)L, (int)HD,
                  D, D, HD, 0, HD, L * D, (int)H, (int)B, iscale);
    }
    softmax_rows<<<(unsigned)(B * H * M), 256, 0, stream>>>(sc_w, pr_w, (int)L);
    // att_w = probs_w @ v_w -> (B,M,D) bf16
    {
      OutDesc o0 = OD0(); o0.b = att_w; o0.ld = D; o0.s1 = HD; o0.s2 = M * D;
      launch_gemm(stream, pr_w, v_wT, o0, OD0(), (int)HD, (int)M, (int)HD, (int)L,
                  L, B * L, M * L, H * M * L, HD * B * L, L, (int)H, (int)B, 1.f);
    }
    // new_mem = att_w @ wo_w -> fp32 + bf16
    float* nmf = (i == 0) ? mem_f : nm_f;
    u16*   nmb = (i == 0) ? mem_b : nm_b;
    {
      OutDesc o0 = OD0(); o0.f = nmf; o0.b = nmb; o0.ld = D;
      launch_gemm(stream, att_w, wowT, o0, OD0(), (int)D, (int)(B * M), (int)D, (int)D,
                  D, D, 0, 0, 0, 0, 1, 1, 1.f);
    }
    if (i > 0) {
      concat_mem<<<(unsigned)(B * M * 2 * D / 256), 256, 0, stream>>>(mem_b, nm_b, cat);
      {
        OutDesc o0 = OD0(); o0.f = gpre_w; o0.ld = D; o0.bias = bg_w;
        launch_gemm(stream, cat, wgwT, o0, OD0(), (int)D, (int)(B * M), (int)D, (int)(2 * D),
                    2 * D, 2 * D, 0, 0, 0, 0, 1, 1, 1.f);
      }
      update_mem<<<(unsigned)(B * M * D / 256), 256, 0, stream>>>(gpre_w, nm_f, mem_f, mem_b);
    }
  }
}